// Round 2
// baseline (278.270 us; speedup 1.0000x reference)
//
#include <hip/hip_runtime.h>

#define DD 256
#define KK 1024
#define HW 4096
#define NROWSZ 65536
#define OUT_Z 16777216
#define OUT_IDX OUT_Z
#define OUT_LOSS (OUT_Z + NROWSZ)

#define MARGIN 4.5e-4f

// ws layout (bytes)
#define WS_ESQ   0          // float[1024]
#define WS_EH    4096       // _Float16[262144] emb fp16 [k][d]
#define WS_HLIST 528384     // int[65536]
#define WS_HCNT  790528     // int
#define WS_LSUM  790536     // double
#define WS_EMBT  791552     // float[256*1024] = 1 MB, emb^T [d][k]
#define WS_HZ    1840128    // float[hzcap*256] compact exact fp32 z rows (hard rows)

typedef _Float16 f16x8 __attribute__((ext_vector_type(8)));
typedef float f32x4 __attribute__((ext_vector_type(4)));
union U16x8 { uint4 u; f16x8 h; };
typedef unsigned long long u64;

static __device__ __forceinline__ u64 umin64(u64 a, u64 b) { return a < b ? a : b; }
static __device__ __forceinline__ unsigned pk16(float a, float b) {
    _Float16 ha = (_Float16)a, hb = (_Float16)b;
    return (unsigned)__builtin_bit_cast(unsigned short, ha)
         | ((unsigned)__builtin_bit_cast(unsigned short, hb) << 16);
}
static __device__ __forceinline__ void gl_lds16(const void* g, void* l) {
    __builtin_amdgcn_global_load_lds(
        (const __attribute__((address_space(1))) unsigned int*)g,
        (__attribute__((address_space(3))) unsigned int*)l, 16, 0, 0);
}

// ---------------- prep: esq (numpy pairwise-8 exact), eh fp16, embT fp32, init -----
__global__ void vq_prep(const float* __restrict__ emb, float* __restrict__ esq,
                        uint2* __restrict__ eh2, int* __restrict__ hcnt,
                        double* __restrict__ lsum, float* __restrict__ embT,
                        int use_embT)
{
    const int bid = blockIdx.x;
    const int t = threadIdx.x;
    if (bid == 0 && t == 0) { *hcnt = 0; *lsum = 0.0; }

    if (bid < 4) {
        int k = bid * 256 + t;
        const float* e = emb + (size_t)k * DD;
        float blk[2];
#pragma unroll
        for (int b2 = 0; b2 < 2; ++b2) {
            const float* p = e + b2 * 128;
            float r[8];
#pragma unroll
            for (int j = 0; j < 8; ++j) r[j] = __fmul_rn(p[j], p[j]);
            for (int i = 8; i < 128; i += 8) {
#pragma unroll
                for (int j = 0; j < 8; ++j)
                    r[j] = __fadd_rn(r[j], __fmul_rn(p[i + j], p[i + j]));
            }
            blk[b2] = __fadd_rn(__fadd_rn(__fadd_rn(r[0], r[1]), __fadd_rn(r[2], r[3])),
                                __fadd_rn(__fadd_rn(r[4], r[5]), __fadd_rn(r[6], r[7])));
        }
        esq[k] = __fadd_rn(blk[0], blk[1]);
    } else if (bid < 20) {
        int tid = (bid - 4) * 256 + t;
        const float4* e4 = (const float4*)emb;
#pragma unroll
        for (int i = 0; i < 16; ++i) {
            int idx = i * 4096 + tid;
            float4 v = e4[idx];
            eh2[idx] = make_uint2(pk16(v.x, v.y), pk16(v.z, v.w));
        }
    } else {
        if (!use_embT) return;
        int u = bid - 20;              // 0..15
        int k = u * 64 + (t >> 2);
        int c = t & 3;
        const float4* e4 = (const float4*)(emb + (size_t)k * DD);
#pragma unroll
        for (int i = 0; i < 16; ++i) {
            float4 v = e4[c * 16 + i];
            int d = c * 64 + i * 4;
            embT[(size_t)(d + 0) * KK + k] = v.x;
            embT[(size_t)(d + 1) * KK + k] = v.y;
            embT[(size_t)(d + 2) * KK + k] = v.z;
            embT[(size_t)(d + 3) * KK + k] = v.w;
        }
    }
}

// ---------------- score: tiled MFMA GEMM, LDS-staged B, swizzled operands ----------
// LDS map (bytes):
//   [    0, 32768)  zh   : fp16 z tile [64 rows][256 d], 16B-XOR swizzled by row&7
//   [32768, 65536)  ebuf : 2 x 16 KB code tiles (32 codes x 512B), swizzled by code&7
//   [65536, 69632)  esq_s: float[1024]
//   [69632, 70656)  cand : uint2[64][2]
//   [70656, 70912)  idxs : int[64]
//   [70912, 70928)  wsum : float[4]
//   er (fp32 emb rows [64][256], rotated) reuses [0, 65536) after the main loop.
__launch_bounds__(256, 2)
__global__ void vq_score(const float* __restrict__ z, const float* __restrict__ emb,
                         const _Float16* __restrict__ eh, const float* __restrict__ esq,
                         float* __restrict__ out, int* __restrict__ hlist,
                         int* __restrict__ hcnt, double* __restrict__ lsum,
                         float* __restrict__ hz, int hzcap)
{
    __shared__ __align__(16) char smem[70928];
    char* ebufc = smem + 32768;
    float* esq_s = (float*)(smem + 65536);
    uint2 (*cand)[2] = (uint2 (*)[2])(smem + 69632);
    int* idxs = (int*)(smem + 70656);
    float* wsum = (float*)(smem + 70912);
    float* er = (float*)smem;

    const int t = threadIdx.x;
    const int lane = t & 63;
    const int w = t >> 6;
    const int col = lane & 15;
    const int quad = lane >> 4;
    const int wr = w >> 1;          // row half (0,1): rows [wr*32, wr*32+32)
    const int wc = w & 1;           // code half within each tile

    const int n0 = blockIdx.x * 64;
    const int b = n0 >> 12;
    const int hw0 = n0 & (HW - 1);
    const float* zbase = z + (size_t)b * DD * HW;

    // ---- phase 1: stage z -> zh fp16 (swizzled) + esq -> LDS
    {
        const int r = t & 63, dg = t >> 6;
        const float* src = zbase + hw0 + r;
#pragma unroll
        for (int i = 0; i < 8; ++i) {
            const int d0 = dg * 64 + i * 8;
            float v0 = src[(size_t)(d0 + 0) * HW];
            float v1 = src[(size_t)(d0 + 1) * HW];
            float v2 = src[(size_t)(d0 + 2) * HW];
            float v3 = src[(size_t)(d0 + 3) * HW];
            float v4 = src[(size_t)(d0 + 4) * HW];
            float v5 = src[(size_t)(d0 + 5) * HW];
            float v6 = src[(size_t)(d0 + 6) * HW];
            float v7 = src[(size_t)(d0 + 7) * HW];
            uint4 pk = make_uint4(pk16(v0, v1), pk16(v2, v3), pk16(v4, v5), pk16(v6, v7));
            *(uint4*)(smem + r * 512 + ((d0 * 2) ^ ((r & 7) << 4))) = pk;
        }
        esq_s[t] = esq[t];
        esq_s[256 + t] = esq[256 + t];
        esq_s[512 + t] = esq[512 + t];
        esq_s[768 + t] = esq[768 + t];
    }
    __syncthreads();

    const char* ehB = (const char*)eh;
    auto stage_tile = [&](int tt, int bufsel) {
#pragma unroll
        for (int i = 0; i < 4; ++i) {
            int pbyte = (w * 4 + i) * 1024 + lane * 16;
            int soff = pbyte ^ (((pbyte >> 9) & 7) << 4);   // pre-swizzled source
            gl_lds16(ehB + (size_t)tt * 16384 + soff,
                     ebufc + bufsel * 16384 + (w * 4 + i) * 1024);
        }
    };
    stage_tile(0, 0);

    // ---- A-fragments (32 rows of this wave) into 64 VGPRs
    U16x8 af[2][8];
#pragma unroll
    for (int nt = 0; nt < 2; ++nt)
#pragma unroll
        for (int ds = 0; ds < 8; ++ds)
            af[nt][ds].u = *(const uint4*)(smem + (wr * 32 + nt * 16 + col) * 512
                                           + ((ds * 64 + quad * 16) ^ ((col & 7) << 4)));
    __syncthreads();   // tile 0 staged (vmcnt drained), af reads done

    unsigned t1[8], t2[8];
#pragma unroll
    for (int i = 0; i < 8; ++i) { t1[i] = 0xFFFFFFFFu; t2[i] = 0xFFFFFFFFu; }

    const int cbyte = (wc * 16 + col) * 512;
    const int swzc = (col & 7) << 4;

    for (int tt = 0; tt < 32; ++tt) {
        const int cur = tt & 1;
        if (tt + 1 < 32) stage_tile(tt + 1, cur ^ 1);

        const char* bbuf = ebufc + cur * 16384 + cbyte;
        const int code = tt * 32 + wc * 16 + col;
        const float eq1 = 1.0f + esq_s[code];

        f32x4 acc0 = (f32x4)0.0f, acc1 = (f32x4)0.0f;
#pragma unroll
        for (int ds = 0; ds < 8; ++ds) {
            U16x8 bf;
            bf.u = *(const uint4*)(bbuf + ((ds * 64 + quad * 16) ^ swzc));
            acc0 = __builtin_amdgcn_mfma_f32_16x16x32_f16(af[0][ds].h, bf.h, acc0, 0, 0, 0);
            acc1 = __builtin_amdgcn_mfma_f32_16x16x32_f16(af[1][ds].h, bf.h, acc1, 0, 0, 0);
        }
        // s' = 1 + esq - 2*dot  > 0  => IEEE bits monotone; key = bits&~1023 | code
#pragma unroll
        for (int r = 0; r < 4; ++r) {
            float s0 = fmaf(-2.0f, acc0[r], eq1);
            unsigned k0 = (__float_as_uint(s0) & 0xFFFFFC00u) | (unsigned)code;
            t2[r] = min(t2[r], max(t1[r], k0));
            t1[r] = min(t1[r], k0);
            float s1 = fmaf(-2.0f, acc1[r], eq1);
            unsigned k1 = (__float_as_uint(s1) & 0xFFFFFC00u) | (unsigned)code;
            t2[4 + r] = min(t2[4 + r], max(t1[4 + r], k1));
            t1[4 + r] = min(t1[4 + r], k1);
        }
        __syncthreads();   // drains stage(tt+1); protects buf reuse
    }

    // ---- cross-col (16-lane) top2 merge; exclusive (row, wc) ownership
#pragma unroll
    for (int mi = 0; mi < 8; ++mi) {
        unsigned a = t1[mi], bb = t2[mi];
#pragma unroll
        for (int off = 1; off < 16; off <<= 1) {
            unsigned o1 = __shfl_xor(a, off, 16);
            unsigned o2 = __shfl_xor(bb, off, 16);
            unsigned mx = max(a, o1);
            a = min(a, o1);
            bb = min(min(bb, o2), mx);
        }
        if (col == 0)
            cand[wr * 32 + (mi >> 2) * 16 + quad * 4 + (mi & 3)][wc] = make_uint2(a, bb);
    }
    __syncthreads();

    // ---- merge 2 code-halves + margin routing
    if (t < 64) {
        uint2 c0 = cand[t][0], c1 = cand[t][1];
        unsigned mx = max(c0.x, c1.x);
        unsigned a = min(c0.x, c1.x);
        unsigned bb = min(min(c0.y, c1.y), mx);
        float s1 = __uint_as_float(a & 0xFFFFFC00u);
        float s2 = __uint_as_float(bb & 0xFFFFFC00u);
        int k1 = (int)(a & 1023u);
        if (__fsub_rn(s2, s1) > MARGIN) {
            idxs[t] = k1;
            out[OUT_IDX + n0 + t] = (float)k1;
        } else {
            int pos = atomicAdd(hcnt, 1);
            hlist[pos] = n0 + t;
            idxs[t] = -2 - pos;
        }
    }
    __syncthreads();

    // ---- er fill: winning emb rows -> LDS (4 lanes x float4 per row, rotated layout)
    {
        const int row = t >> 2;
        const int cl = t & 3;
        int idx = idxs[row];
        if (idx >= 0) {
            const float4* e4 = (const float4*)(emb + (size_t)idx * DD);
#pragma unroll
            for (int i = 0; i < 16; ++i) {
                int ch = i * 4 + cl;            // 0..63
                int d0 = ch * 4;
                float4 v = e4[ch];
                *(float4*)&er[row * 256 + ((d0 + row * 4) & 255)] = v;
            }
        }
    }
    __syncthreads();

    // ---- scatter + loss (certain) / hz stash (hard); exact z re-read from global
    {
        const int rr = t & 63, dg = t >> 6;
        int idx = idxs[rr];
        float lacc = 0.f;
        const float* zcol = zbase + hw0 + rr;
        if (idx >= 0) {
            float* oc = out + (size_t)b * DD * HW + hw0 + rr;
#pragma unroll 4
            for (int i = 0; i < 16; ++i) {
                int d0 = dg * 64 + i * 4;
                float4 e4 = *(const float4*)&er[rr * 256 + ((d0 + rr * 4) & 255)];
                float z0 = zcol[(size_t)(d0 + 0) * HW];
                float z1 = zcol[(size_t)(d0 + 1) * HW];
                float z2 = zcol[(size_t)(d0 + 2) * HW];
                float z3 = zcol[(size_t)(d0 + 3) * HW];
                oc[(size_t)(d0 + 0) * HW] = e4.x;
                oc[(size_t)(d0 + 1) * HW] = e4.y;
                oc[(size_t)(d0 + 2) * HW] = e4.z;
                oc[(size_t)(d0 + 3) * HW] = e4.w;
                float df;
                df = e4.x - z0; lacc = fmaf(df, df, lacc);
                df = e4.y - z1; lacc = fmaf(df, df, lacc);
                df = e4.z - z2; lacc = fmaf(df, df, lacc);
                df = e4.w - z3; lacc = fmaf(df, df, lacc);
            }
        } else {
            int pos = -2 - idx;
            if (pos < hzcap) {
                float4* dst = (float4*)(hz + (size_t)pos * DD);
#pragma unroll 4
                for (int i = 0; i < 16; ++i) {
                    int d0 = dg * 64 + i * 4;
                    float4 v;
                    v.x = zcol[(size_t)(d0 + 0) * HW];
                    v.y = zcol[(size_t)(d0 + 1) * HW];
                    v.z = zcol[(size_t)(d0 + 2) * HW];
                    v.w = zcol[(size_t)(d0 + 3) * HW];
                    dst[d0 >> 2] = v;
                }
            }
        }
#pragma unroll
        for (int off = 32; off > 0; off >>= 1) lacc += __shfl_down(lacc, off, 64);
        if (lane == 0) wsum[w] = lacc;
    }
    __syncthreads();
    if (t == 0) {
        double tot = (double)wsum[0] + (double)wsum[1] + (double)wsum[2] + (double)wsum[3];
        atomicAdd(lsum, tot);
    }
}

// ---- hard-path dot products: codes k = 4t+kk, sequential-d fma chain (bit-exact)
template<int USET>
static __device__ __forceinline__ void dot_codes(const float4* __restrict__ embT4,
                                                 const float4* __restrict__ emb4,
                                                 const float4* __restrict__ zb4,
                                                 int t, float (&acc_)[8][4])
{
#pragma unroll 2
    for (int dc = 0; dc < 64; ++dc) {
        float4 e0, e1, e2, e3;
        if (USET) {
            e0 = embT4[(size_t)(dc * 4 + 0) * 256 + t];
            e1 = embT4[(size_t)(dc * 4 + 1) * 256 + t];
            e2 = embT4[(size_t)(dc * 4 + 2) * 256 + t];
            e3 = embT4[(size_t)(dc * 4 + 3) * 256 + t];
        } else {
            float4 a0 = emb4[(size_t)(4 * t + 0) * 64 + dc];
            float4 a1 = emb4[(size_t)(4 * t + 1) * 64 + dc];
            float4 a2 = emb4[(size_t)(4 * t + 2) * 64 + dc];
            float4 a3 = emb4[(size_t)(4 * t + 3) * 64 + dc];
            e0 = make_float4(a0.x, a1.x, a2.x, a3.x);
            e1 = make_float4(a0.y, a1.y, a2.y, a3.y);
            e2 = make_float4(a0.z, a1.z, a2.z, a3.z);
            e3 = make_float4(a0.w, a1.w, a2.w, a3.w);
        }
#pragma unroll
        for (int j = 0; j < 8; ++j) {
            float4 zv = zb4[j * 64 + dc];
            acc_[j][0] = fmaf(zv.x, e0.x, acc_[j][0]);
            acc_[j][1] = fmaf(zv.x, e0.y, acc_[j][1]);
            acc_[j][2] = fmaf(zv.x, e0.z, acc_[j][2]);
            acc_[j][3] = fmaf(zv.x, e0.w, acc_[j][3]);
            acc_[j][0] = fmaf(zv.y, e1.x, acc_[j][0]);
            acc_[j][1] = fmaf(zv.y, e1.y, acc_[j][1]);
            acc_[j][2] = fmaf(zv.y, e1.z, acc_[j][2]);
            acc_[j][3] = fmaf(zv.y, e1.w, acc_[j][3]);
            acc_[j][0] = fmaf(zv.z, e2.x, acc_[j][0]);
            acc_[j][1] = fmaf(zv.z, e2.y, acc_[j][1]);
            acc_[j][2] = fmaf(zv.z, e2.z, acc_[j][2]);
            acc_[j][3] = fmaf(zv.z, e2.w, acc_[j][3]);
            acc_[j][0] = fmaf(zv.w, e3.x, acc_[j][0]);
            acc_[j][1] = fmaf(zv.w, e3.y, acc_[j][1]);
            acc_[j][2] = fmaf(zv.w, e3.z, acc_[j][2]);
            acc_[j][3] = fmaf(zv.w, e3.w, acc_[j][3]);
        }
    }
}

// ---------------- hard: exact fp32 rescan, barrier-free inner loop -----------------
__launch_bounds__(256)
__global__ void vq_hard(const float* __restrict__ z, const float* __restrict__ emb,
                        const float* __restrict__ embT, const float* __restrict__ esq,
                        const float* __restrict__ hz, const int* __restrict__ hlist,
                        const int* __restrict__ hcnt, float* __restrict__ out,
                        double* __restrict__ lsum, int hzcap, int use_embT)
{
    __shared__ __align__(16) float zbuf[8 * 256];
    __shared__ float chains[8][16];
    __shared__ float zq_s[8];
    __shared__ int rows_s[8];
    __shared__ int idx_s[8];
    __shared__ u64 red[4][8];
    __shared__ float wsum[4];

    const int t = threadIdx.x;
    const int lane = t & 63;
    const int w = t >> 6;
    const int count = *hcnt;
    float lacc = 0.f;

    const float4* embT4 = (const float4*)embT;
    const float4* emb4 = (const float4*)emb;
    const float4* hz4 = (const float4*)hz;
    const float4* zb4 = (const float4*)zbuf;
    const float4 eqv4 = ((const float4*)esq)[t];
    const float eqa[4] = {eqv4.x, eqv4.y, eqv4.z, eqv4.w};

    for (int g = blockIdx.x; g * 8 < count; g += gridDim.x) {
        __syncthreads();
        if (t < 8) {
            int p = g * 8 + t;
            rows_s[t] = (p < count) ? hlist[p] : -1;
        }
        __syncthreads();

        {
            const int j = t >> 5, dpos = t & 31;
            const int pos = g * 8 + j;
            const int r = rows_s[j];
            float4 v0 = make_float4(0.f, 0.f, 0.f, 0.f), v1 = v0;
            if (r >= 0) {
                if (pos < hzcap) {
                    v0 = hz4[(size_t)pos * 64 + dpos * 2];
                    v1 = hz4[(size_t)pos * 64 + dpos * 2 + 1];
                } else {
                    const float* zp = z + (size_t)(r >> 12) * (DD * HW) + (r & (HW - 1));
                    const int d0 = dpos * 8;
                    v0.x = zp[(size_t)(d0 + 0) * HW];
                    v0.y = zp[(size_t)(d0 + 1) * HW];
                    v0.z = zp[(size_t)(d0 + 2) * HW];
                    v0.w = zp[(size_t)(d0 + 3) * HW];
                    v1.x = zp[(size_t)(d0 + 4) * HW];
                    v1.y = zp[(size_t)(d0 + 5) * HW];
                    v1.z = zp[(size_t)(d0 + 6) * HW];
                    v1.w = zp[(size_t)(d0 + 7) * HW];
                }
            }
            *(float4*)&zbuf[j * 256 + dpos * 8] = v0;
            *(float4*)&zbuf[j * 256 + dpos * 8 + 4] = v1;
        }
        __syncthreads();

        if (t < 128) {
            int j = t >> 4, c = t & 15, b2 = c >> 3, jj = c & 7;
            const float* p = &zbuf[j * 256];
            int base = b2 * 128 + jj;
            float v = p[base];
            float acc = __fmul_rn(v, v);
            for (int i = 1; i < 16; ++i) {
                float u = p[base + i * 8];
                acc = __fadd_rn(acc, __fmul_rn(u, u));
            }
            chains[j][c] = acc;
        }
        __syncthreads();
        if (t < 8) {
            const float* c = chains[t];
            float b0 = __fadd_rn(__fadd_rn(__fadd_rn(c[0], c[1]), __fadd_rn(c[2], c[3])),
                                 __fadd_rn(__fadd_rn(c[4], c[5]), __fadd_rn(c[6], c[7])));
            float b1 = __fadd_rn(__fadd_rn(__fadd_rn(c[8], c[9]), __fadd_rn(c[10], c[11])),
                                 __fadd_rn(__fadd_rn(c[12], c[13]), __fadd_rn(c[14], c[15])));
            zq_s[t] = __fadd_rn(b0, b1);
        }
        __syncthreads();

        float acc_[8][4];
#pragma unroll
        for (int j = 0; j < 8; ++j)
#pragma unroll
            for (int kk = 0; kk < 4; ++kk) acc_[j][kk] = 0.0f;

        if (use_embT) dot_codes<1>(embT4, emb4, zb4, t, acc_);
        else          dot_codes<0>(embT4, emb4, zb4, t, acc_);

#pragma unroll
        for (int j = 0; j < 8; ++j) {
            u64 m = ~0ull;
#pragma unroll
            for (int kk = 0; kk < 4; ++kk) {
                float s = __fsub_rn(__fadd_rn(zq_s[j], eqa[kk]),
                                    __fmul_rn(2.0f, acc_[j][kk]));
                u64 p = ((u64)__float_as_uint(s) << 32) | (unsigned)(4 * t + kk);
                m = umin64(m, p);
            }
#pragma unroll
            for (int off = 1; off < 64; off <<= 1)
                m = umin64(m, __shfl_xor(m, off, 64));
            if (lane == 0) red[w][j] = m;
        }
        __syncthreads();
        if (t < 8) {
            u64 m = umin64(umin64(red[0][t], red[1][t]), umin64(red[2][t], red[3][t]));
            int ki = (int)(m & 0xffffffffu);
            idx_s[t] = ki;
            int r = rows_s[t];
            if (r >= 0) out[OUT_IDX + r] = (float)ki;
        }
        __syncthreads();

        for (int p = t; p < 2048; p += 256) {
            int j = p >> 8, d = p & 255;
            int r = rows_s[j];
            if (r >= 0) {
                float e = emb[(size_t)idx_s[j] * DD + d];
                size_t off = (size_t)(r >> 12) * (DD * HW) + (size_t)d * HW + (r & (HW - 1));
                float zv = zbuf[j * 256 + d];
                out[off] = e;
                float df = e - zv;
                lacc = fmaf(df, df, lacc);
            }
        }
    }

#pragma unroll
    for (int off = 32; off > 0; off >>= 1) lacc += __shfl_down(lacc, off, 64);
    if (lane == 0) wsum[w] = lacc;
    __syncthreads();
    if (t == 0) {
        double tot = (double)wsum[0] + (double)wsum[1] + (double)wsum[2] + (double)wsum[3];
        if (tot != 0.0) atomicAdd(lsum, tot);
    }
}

__global__ void vq_final(const double* __restrict__ lsum, float* __restrict__ out)
{
    out[OUT_LOSS] = (float)(0.25 * (lsum[0] / (double)OUT_Z));
}

extern "C" void kernel_launch(void* const* d_in, const int* in_sizes, int n_in,
                              void* d_out, int out_size, void* d_ws, size_t ws_size,
                              hipStream_t stream)
{
    const float* z = (const float*)d_in[0];
    const float* emb = (const float*)d_in[1];
    float* out = (float*)d_out;
    char* w = (char*)d_ws;

    float* esq = (float*)(w + WS_ESQ);
    _Float16* eh = (_Float16*)(w + WS_EH);
    uint2* eh2 = (uint2*)(w + WS_EH);
    int* hlist = (int*)(w + WS_HLIST);
    int* hcnt = (int*)(w + WS_HCNT);
    double* lsum = (double*)(w + WS_LSUM);
    float* embT = (float*)(w + WS_EMBT);
    float* hz = (float*)(w + WS_HZ);

    int use_embT = (ws_size >= (size_t)WS_EMBT + (size_t)DD * KK * sizeof(float)) ? 1 : 0;
    int hzcap = 0;
    if (ws_size > (size_t)WS_HZ) {
        size_t c = (ws_size - (size_t)WS_HZ) / ((size_t)DD * sizeof(float));
        hzcap = (c > (size_t)NROWSZ) ? NROWSZ : (int)c;
    }

    vq_prep<<<dim3(36), dim3(256), 0, stream>>>(emb, esq, eh2, hcnt, lsum, embT, use_embT);
    vq_score<<<dim3(1024), dim3(256), 0, stream>>>(z, emb, eh, esq, out, hlist, hcnt, lsum,
                                                   hz, hzcap);
    vq_hard<<<dim3(1024), dim3(256), 0, stream>>>(z, emb, embT, esq, hz, hlist, hcnt, out,
                                                  lsum, hzcap, use_embT);
    vq_final<<<dim3(1), dim3(1), 0, stream>>>(lsum, out);
}

// Round 3
// 271.880 us; speedup vs baseline: 1.0235x; 1.0235x over previous
//
#include <hip/hip_runtime.h>

#define DD 256
#define KK 1024
#define HW 4096
#define NROWSZ 65536
#define OUT_Z 16777216
#define OUT_IDX OUT_Z
#define OUT_LOSS (OUT_Z + NROWSZ)

#define MARGIN 4.5e-4f

// ws layout (bytes)
#define WS_ESQ   0          // float[1024]
#define WS_EH    4096       // _Float16[262144] emb fp16 [k][d] (fallback B path)
#define WS_HLIST 528384     // int[65536]
#define WS_HCNT  790528     // int
#define WS_LSUM  790536     // double
#define WS_EMBT  791552     // float[256*1024] = 1 MB, emb^T [d][k]
#define WS_EHP   1840128    // _Float16 fragment-ordered emb: 512 KB, [tt][wc][ds][lane] uint4

// ztF (fp16 A-fragments, 32 MB) lives in the out buffer's z_q region [0, 32MB),
// which is only written with final values by vq_out (after score consumes ztF).

typedef _Float16 f16x8 __attribute__((ext_vector_type(8)));
typedef float f32x4 __attribute__((ext_vector_type(4)));
union U16x8 { uint4 u; f16x8 h; };
typedef unsigned long long u64;

static __device__ __forceinline__ u64 umin64(u64 a, u64 b) { return a < b ? a : b; }
static __device__ __forceinline__ unsigned pk16(float a, float b) {
    _Float16 ha = (_Float16)a, hb = (_Float16)b;
    return (unsigned)__builtin_bit_cast(unsigned short, ha)
         | ((unsigned)__builtin_bit_cast(unsigned short, hb) << 16);
}

// ---------------- prep: esq exact, eh fp16, embT fp32, ehP fragment-order ----------
__global__ void vq_prep(const float* __restrict__ emb, float* __restrict__ esq,
                        uint2* __restrict__ eh2, int* __restrict__ hcnt,
                        double* __restrict__ lsum, float* __restrict__ embT,
                        int use_embT, uint4* __restrict__ ehP, int use_ehp)
{
    const int bid = blockIdx.x;
    const int t = threadIdx.x;
    if (bid == 0 && t == 0) { *hcnt = 0; *lsum = 0.0; }

    if (bid < 4) {
        // esq: numpy pairwise-8 exact
        int k = bid * 256 + t;
        const float* e = emb + (size_t)k * DD;
        float blk[2];
#pragma unroll
        for (int b2 = 0; b2 < 2; ++b2) {
            const float* p = e + b2 * 128;
            float r[8];
#pragma unroll
            for (int j = 0; j < 8; ++j) r[j] = __fmul_rn(p[j], p[j]);
            for (int i = 8; i < 128; i += 8) {
#pragma unroll
                for (int j = 0; j < 8; ++j)
                    r[j] = __fadd_rn(r[j], __fmul_rn(p[i + j], p[i + j]));
            }
            blk[b2] = __fadd_rn(__fadd_rn(__fadd_rn(r[0], r[1]), __fadd_rn(r[2], r[3])),
                                __fadd_rn(__fadd_rn(r[4], r[5]), __fadd_rn(r[6], r[7])));
        }
        esq[k] = __fadd_rn(blk[0], blk[1]);
    } else if (bid < 20) {
        // eh fp16 [k][d] (fallback)
        int tid = (bid - 4) * 256 + t;
        const float4* e4 = (const float4*)emb;
#pragma unroll
        for (int i = 0; i < 16; ++i) {
            int idx = i * 4096 + tid;
            float4 v = e4[idx];
            eh2[idx] = make_uint2(pk16(v.x, v.y), pk16(v.z, v.w));
        }
    } else if (bid < 36) {
        // embT [d][k] fp32
        if (!use_embT) return;
        int u = bid - 20;
        int k = u * 64 + (t >> 2);
        int c = t & 3;
        const float4* e4 = (const float4*)(emb + (size_t)k * DD);
#pragma unroll
        for (int i = 0; i < 16; ++i) {
            float4 v = e4[c * 16 + i];
            int d = c * 64 + i * 4;
            embT[(size_t)(d + 0) * KK + k] = v.x;
            embT[(size_t)(d + 1) * KK + k] = v.y;
            embT[(size_t)(d + 2) * KK + k] = v.z;
            embT[(size_t)(d + 3) * KK + k] = v.w;
        }
    } else {
        // ehP: fragment-ordered fp16 B. uint4 index L = ((tt*2+wc)*8+ds)*64 + lane
        // holds eh[tt*32 + wc*16 + (lane&15)][ds*32 + (lane>>4)*8 .. +8]
        if (!use_ehp) return;
#pragma unroll
        for (int it = 0; it < 8; ++it) {
            int L = ((bid - 36) * 8 + it) * 256 + t;
            int lane = L & 63, ds = (L >> 6) & 7, wcq = (L >> 9) & 1, tt = L >> 10;
            int col = lane & 15, quad = lane >> 4;
            int code = tt * 32 + wcq * 16 + col;
            int d0 = ds * 32 + quad * 8;
            const float* e = emb + (size_t)code * DD + d0;
            float4 a = *(const float4*)e;
            float4 c4 = *(const float4*)(e + 4);
            ehP[L] = make_uint4(pk16(a.x, a.y), pk16(a.z, a.w),
                                pk16(c4.x, c4.y), pk16(c4.z, c4.w));
        }
    }
}

// ---------------- zt: z (NCHW fp32) -> ztF (fp16, MFMA A-fragment order) -----------
// block = (b, hwt of 256 hw, dt of 64 d); contiguous 1KB reads + 1KB writes.
__launch_bounds__(256)
__global__ void vq_zt(const float* __restrict__ z, float* out)
{
    __shared__ __align__(16) char lt[256 * 128];   // fp16 [hw][64 d], XOR-swizzled
    uint4* ztF = (uint4*)out;

    const int t = threadIdx.x;
    const int lane = t & 63;
    const int w = t >> 6;
    const int bid = blockIdx.x;
    const int bb = bid >> 6;            // 0..15
    const int hwt = (bid >> 2) & 15;    // 0..15 (256 hw each)
    const int dt = bid & 3;             // 0..3  (64 d each)

    // stage: wave w covers dd = w*16 .. +16; lanes cover 256 hw as float4
    {
        const float* src = z + ((size_t)bb * DD + dt * 64) * HW + hwt * 256 + lane * 4;
#pragma unroll
        for (int i = 0; i < 16; ++i) {
            const int dd = w * 16 + i;
            float4 v = *(const float4*)(src + (size_t)dd * HW);
            float va[4] = {v.x, v.y, v.z, v.w};
#pragma unroll
            for (int c = 0; c < 4; ++c) {
                const int hwl = lane * 4 + c;
                const int sw = ((hwl >> 2) & 7) << 4;
                *(_Float16*)(lt + hwl * 128 + ((dd * 2) ^ sw)) = (_Float16)va[c];
            }
        }
    }
    __syncthreads();

    // write: wave w emits local tile w (64 hw) as fragment-ordered uint4 chunks
    {
        const size_t gt = (size_t)bb * 64 + hwt * 4 + w;   // global 64-row tile id
        const int col = lane & 15, quad = lane >> 4;
#pragma unroll
        for (int f = 0; f < 4; ++f) {
            const int hwl = w * 64 + f * 16 + col;
            const int sw = ((hwl >> 2) & 7) << 4;
#pragma unroll
            for (int dsl = 0; dsl < 2; ++dsl) {
                const int dloc = dsl * 32 + quad * 8;
                uint4 val = *(const uint4*)(lt + hwl * 128 + ((dloc * 2) ^ sw));
                ztF[((gt * 4 + f) * 8 + (dt * 2 + dsl)) * 64 + lane] = val;
            }
        }
    }
}

// ---------------- score: barrier-free register MFMA; writes idx + hard list --------
__launch_bounds__(256, 2)
__global__ void vq_score(float* out, const _Float16* __restrict__ eh,
                         const uint4* __restrict__ ehP, const float* __restrict__ esq,
                         int* __restrict__ hlist, int* __restrict__ hcnt, int use_ehp)
{
    __shared__ float esq_s[1024];
    __shared__ uint2 cand[64][2];

    const uint4* ztF = (const uint4*)out;
    const int t = threadIdx.x;
    const int lane = t & 63;
    const int w = t >> 6;
    const int col = lane & 15;
    const int quad = lane >> 4;
    const int wr = w >> 1;          // row half: rows [wr*32, wr*32+32)
    const int wc = w & 1;           // code half of each 32-code tile

    const int gt = blockIdx.x;      // 64-row tile
    const int n0 = gt * 64;

    esq_s[t] = esq[t];
    esq_s[256 + t] = esq[256 + t];
    esq_s[512 + t] = esq[512 + t];
    esq_s[768 + t] = esq[768 + t];

    // A-fragments: 16 coalesced 1KB loads from ztF
    U16x8 af[2][8];
#pragma unroll
    for (int nt = 0; nt < 2; ++nt) {
        const int f = wr * 2 + nt;
#pragma unroll
        for (int ds = 0; ds < 8; ++ds)
            af[nt][ds].u = ztF[(((size_t)gt * 4 + f) * 8 + ds) * 64 + lane];
    }
    __syncthreads();   // esq_s ready

    unsigned t1[8], t2[8];
#pragma unroll
    for (int i = 0; i < 8; ++i) { t1[i] = 0xFFFFFFFFu; t2[i] = 0xFFFFFFFFu; }

    if (use_ehp) {
        const uint4* bp = ehP + (size_t)wc * 512 + lane;   // [tt][wc][ds][lane]
#pragma unroll 2
        for (int tt = 0; tt < 32; ++tt) {
            const uint4* p = bp + (size_t)tt * 1024;
            U16x8 bf[8];
#pragma unroll
            for (int ds = 0; ds < 8; ++ds) bf[ds].u = p[ds * 64];
            const int code = tt * 32 + wc * 16 + col;
            const float eq1 = 1.0f + esq_s[code];
            f32x4 acc0 = (f32x4)0.0f, acc1 = (f32x4)0.0f;
#pragma unroll
            for (int ds = 0; ds < 8; ++ds) {
                acc0 = __builtin_amdgcn_mfma_f32_16x16x32_f16(af[0][ds].h, bf[ds].h, acc0, 0, 0, 0);
                acc1 = __builtin_amdgcn_mfma_f32_16x16x32_f16(af[1][ds].h, bf[ds].h, acc1, 0, 0, 0);
            }
#pragma unroll
            for (int r = 0; r < 4; ++r) {
                float s0 = fmaf(-2.0f, acc0[r], eq1);
                unsigned k0 = (__float_as_uint(s0) & 0xFFFFFC00u) | (unsigned)code;
                t2[r] = min(t2[r], max(t1[r], k0));
                t1[r] = min(t1[r], k0);
                float s1 = fmaf(-2.0f, acc1[r], eq1);
                unsigned k1 = (__float_as_uint(s1) & 0xFFFFFC00u) | (unsigned)code;
                t2[4 + r] = min(t2[4 + r], max(t1[4 + r], k1));
                t1[4 + r] = min(t1[4 + r], k1);
            }
        }
    } else {
        const uint4* ehq = (const uint4*)eh;
        for (int tt = 0; tt < 32; ++tt) {
            const int code = tt * 32 + wc * 16 + col;
            const uint4* bp = ehq + (size_t)code * 32 + quad;
            U16x8 bf[8];
#pragma unroll
            for (int ds = 0; ds < 8; ++ds) bf[ds].u = bp[ds * 4];
            const float eq1 = 1.0f + esq_s[code];
            f32x4 acc0 = (f32x4)0.0f, acc1 = (f32x4)0.0f;
#pragma unroll
            for (int ds = 0; ds < 8; ++ds) {
                acc0 = __builtin_amdgcn_mfma_f32_16x16x32_f16(af[0][ds].h, bf[ds].h, acc0, 0, 0, 0);
                acc1 = __builtin_amdgcn_mfma_f32_16x16x32_f16(af[1][ds].h, bf[ds].h, acc1, 0, 0, 0);
            }
#pragma unroll
            for (int r = 0; r < 4; ++r) {
                float s0 = fmaf(-2.0f, acc0[r], eq1);
                unsigned k0 = (__float_as_uint(s0) & 0xFFFFFC00u) | (unsigned)code;
                t2[r] = min(t2[r], max(t1[r], k0));
                t1[r] = min(t1[r], k0);
                float s1 = fmaf(-2.0f, acc1[r], eq1);
                unsigned k1 = (__float_as_uint(s1) & 0xFFFFFC00u) | (unsigned)code;
                t2[4 + r] = min(t2[4 + r], max(t1[4 + r], k1));
                t1[4 + r] = min(t1[4 + r], k1);
            }
        }
    }

    // cross-col (16-lane) top2 merge; exclusive (row, wc) ownership
#pragma unroll
    for (int mi = 0; mi < 8; ++mi) {
        unsigned a = t1[mi], bb = t2[mi];
#pragma unroll
        for (int off = 1; off < 16; off <<= 1) {
            unsigned o1 = __shfl_xor(a, off, 16);
            unsigned o2 = __shfl_xor(bb, off, 16);
            unsigned mx = max(a, o1);
            a = min(a, o1);
            bb = min(min(bb, o2), mx);
        }
        if (col == 0)
            cand[wr * 32 + (mi >> 2) * 16 + quad * 4 + (mi & 3)][wc] = make_uint2(a, bb);
    }
    __syncthreads();

    // merge 2 code-halves + margin routing (idx only; hard rows -> hlist)
    if (t < 64) {
        uint2 c0 = cand[t][0], c1 = cand[t][1];
        unsigned mx = max(c0.x, c1.x);
        unsigned a = min(c0.x, c1.x);
        unsigned bb = min(min(c0.y, c1.y), mx);
        float s1 = __uint_as_float(a & 0xFFFFFC00u);
        float s2 = __uint_as_float(bb & 0xFFFFFC00u);
        int k1 = (int)(a & 1023u);
        if (__fsub_rn(s2, s1) > MARGIN) {
            out[OUT_IDX + n0 + t] = (float)k1;
        } else {
            int pos = atomicAdd(hcnt, 1);
            hlist[pos] = n0 + t;
        }
    }
}

// ---- hard-path dot products (bit-exact sequential-d fma chain) --------------------
template<int USET>
static __device__ __forceinline__ void dot_codes(const float4* __restrict__ embT4,
                                                 const float4* __restrict__ emb4,
                                                 const float4* __restrict__ zb4,
                                                 int t, float (&acc_)[8][4])
{
#pragma unroll 2
    for (int dc = 0; dc < 64; ++dc) {
        float4 e0, e1, e2, e3;
        if (USET) {
            e0 = embT4[(size_t)(dc * 4 + 0) * 256 + t];
            e1 = embT4[(size_t)(dc * 4 + 1) * 256 + t];
            e2 = embT4[(size_t)(dc * 4 + 2) * 256 + t];
            e3 = embT4[(size_t)(dc * 4 + 3) * 256 + t];
        } else {
            float4 a0 = emb4[(size_t)(4 * t + 0) * 64 + dc];
            float4 a1 = emb4[(size_t)(4 * t + 1) * 64 + dc];
            float4 a2 = emb4[(size_t)(4 * t + 2) * 64 + dc];
            float4 a3 = emb4[(size_t)(4 * t + 3) * 64 + dc];
            e0 = make_float4(a0.x, a1.x, a2.x, a3.x);
            e1 = make_float4(a0.y, a1.y, a2.y, a3.y);
            e2 = make_float4(a0.z, a1.z, a2.z, a3.z);
            e3 = make_float4(a0.w, a1.w, a2.w, a3.w);
        }
#pragma unroll
        for (int j = 0; j < 8; ++j) {
            float4 zv = zb4[j * 64 + dc];
            acc_[j][0] = fmaf(zv.x, e0.x, acc_[j][0]);
            acc_[j][1] = fmaf(zv.x, e0.y, acc_[j][1]);
            acc_[j][2] = fmaf(zv.x, e0.z, acc_[j][2]);
            acc_[j][3] = fmaf(zv.x, e0.w, acc_[j][3]);
            acc_[j][0] = fmaf(zv.y, e1.x, acc_[j][0]);
            acc_[j][1] = fmaf(zv.y, e1.y, acc_[j][1]);
            acc_[j][2] = fmaf(zv.y, e1.z, acc_[j][2]);
            acc_[j][3] = fmaf(zv.y, e1.w, acc_[j][3]);
            acc_[j][0] = fmaf(zv.z, e2.x, acc_[j][0]);
            acc_[j][1] = fmaf(zv.z, e2.y, acc_[j][1]);
            acc_[j][2] = fmaf(zv.z, e2.z, acc_[j][2]);
            acc_[j][3] = fmaf(zv.z, e2.w, acc_[j][3]);
            acc_[j][0] = fmaf(zv.w, e3.x, acc_[j][0]);
            acc_[j][1] = fmaf(zv.w, e3.y, acc_[j][1]);
            acc_[j][2] = fmaf(zv.w, e3.z, acc_[j][2]);
            acc_[j][3] = fmaf(zv.w, e3.w, acc_[j][3]);
        }
    }
}

// ---------------- hard: exact fp32 rescan -> idx only ------------------------------
__launch_bounds__(256)
__global__ void vq_hard(const float* __restrict__ z, const float* __restrict__ emb,
                        const float* __restrict__ embT, const float* __restrict__ esq,
                        const int* __restrict__ hlist, const int* __restrict__ hcnt,
                        float* __restrict__ out, int use_embT)
{
    __shared__ __align__(16) float zbuf[8 * 256];
    __shared__ float chains[8][16];
    __shared__ float zq_s[8];
    __shared__ int rows_s[8];
    __shared__ u64 red[4][8];

    const int t = threadIdx.x;
    const int lane = t & 63;
    const int w = t >> 6;
    const int count = *hcnt;

    const float4* embT4 = (const float4*)embT;
    const float4* emb4 = (const float4*)emb;
    const float4* zb4 = (const float4*)zbuf;
    const float4 eqv4 = ((const float4*)esq)[t];
    const float eqa[4] = {eqv4.x, eqv4.y, eqv4.z, eqv4.w};

    for (int g = blockIdx.x; g * 8 < count; g += gridDim.x) {
        __syncthreads();
        if (t < 8) {
            int p = g * 8 + t;
            rows_s[t] = (p < count) ? hlist[p] : -1;
        }
        __syncthreads();

        // stage 8 exact fp32 z rows (strided columns; rare rows only)
        {
            const int j = t >> 5, dpos = t & 31;
            const int r = rows_s[j];
            float4 v0 = make_float4(0.f, 0.f, 0.f, 0.f), v1 = v0;
            if (r >= 0) {
                const float* zp = z + (size_t)(r >> 12) * (DD * HW) + (r & (HW - 1));
                const int d0 = dpos * 8;
                v0.x = zp[(size_t)(d0 + 0) * HW];
                v0.y = zp[(size_t)(d0 + 1) * HW];
                v0.z = zp[(size_t)(d0 + 2) * HW];
                v0.w = zp[(size_t)(d0 + 3) * HW];
                v1.x = zp[(size_t)(d0 + 4) * HW];
                v1.y = zp[(size_t)(d0 + 5) * HW];
                v1.z = zp[(size_t)(d0 + 6) * HW];
                v1.w = zp[(size_t)(d0 + 7) * HW];
            }
            *(float4*)&zbuf[j * 256 + dpos * 8] = v0;
            *(float4*)&zbuf[j * 256 + dpos * 8 + 4] = v1;
        }
        __syncthreads();

        // zsq: bit-exact numpy pairwise-8
        if (t < 128) {
            int j = t >> 4, c = t & 15, b2 = c >> 3, jj = c & 7;
            const float* p = &zbuf[j * 256];
            int base = b2 * 128 + jj;
            float v = p[base];
            float acc = __fmul_rn(v, v);
            for (int i = 1; i < 16; ++i) {
                float u = p[base + i * 8];
                acc = __fadd_rn(acc, __fmul_rn(u, u));
            }
            chains[j][c] = acc;
        }
        __syncthreads();
        if (t < 8) {
            const float* c = chains[t];
            float b0 = __fadd_rn(__fadd_rn(__fadd_rn(c[0], c[1]), __fadd_rn(c[2], c[3])),
                                 __fadd_rn(__fadd_rn(c[4], c[5]), __fadd_rn(c[6], c[7])));
            float b1 = __fadd_rn(__fadd_rn(__fadd_rn(c[8], c[9]), __fadd_rn(c[10], c[11])),
                                 __fadd_rn(__fadd_rn(c[12], c[13]), __fadd_rn(c[14], c[15])));
            zq_s[t] = __fadd_rn(b0, b1);
        }
        __syncthreads();

        float acc_[8][4];
#pragma unroll
        for (int j = 0; j < 8; ++j)
#pragma unroll
            for (int kk = 0; kk < 4; ++kk) acc_[j][kk] = 0.0f;

        if (use_embT) dot_codes<1>(embT4, emb4, zb4, t, acc_);
        else          dot_codes<0>(embT4, emb4, zb4, t, acc_);

#pragma unroll
        for (int j = 0; j < 8; ++j) {
            u64 m = ~0ull;
#pragma unroll
            for (int kk = 0; kk < 4; ++kk) {
                float s = __fsub_rn(__fadd_rn(zq_s[j], eqa[kk]),
                                    __fmul_rn(2.0f, acc_[j][kk]));
                u64 p = ((u64)__float_as_uint(s) << 32) | (unsigned)(4 * t + kk);
                m = umin64(m, p);
            }
#pragma unroll
            for (int off = 1; off < 64; off <<= 1)
                m = umin64(m, __shfl_xor(m, off, 64));
            if (lane == 0) red[w][j] = m;
        }
        __syncthreads();
        if (t < 8) {
            u64 m = umin64(umin64(red[0][t], red[1][t]), umin64(red[2][t], red[3][t]));
            int r = rows_s[t];
            if (r >= 0) out[OUT_IDX + r] = (float)(int)(m & 0xffffffffu);
        }
    }
}

// ---------------- out: d-major contiguous scatter + loss for ALL rows --------------
__launch_bounds__(256)
__global__ void vq_out(const float* __restrict__ z, const float* __restrict__ emb,
                       const float* __restrict__ embT, float* out,
                       double* __restrict__ lsum, int use_embT)
{
    __shared__ float et[8 * 1024];   // embT rows [dg*8 .. +8)
    __shared__ float wsum[4];

    const int t = threadIdx.x;
    const int lane = t & 63;
    const int w = t >> 6;
    const int bb = blockIdx.x >> 5;     // batch
    const int dg = blockIdx.x & 31;     // d-group (8 d)

    if (use_embT) {
#pragma unroll
        for (int c = 0; c < 8; ++c)
            *(float4*)&et[c * 1024 + t * 4] =
                *(const float4*)&embT[(size_t)(dg * 8 + c) * KK + t * 4];
    } else {
        for (int i = 0; i < 32; ++i) {
            int kk = i * 256 + t;          // dl = kk>>10, k = kk&1023
            et[kk] = emb[(size_t)(kk & 1023) * DD + dg * 8 + (kk >> 10)];
        }
    }
    __syncthreads();

    float lacc = 0.f;
    const size_t zb = (size_t)bb * DD * HW;
    const float* idxf = out + OUT_IDX + (size_t)bb * HW;
#pragma unroll
    for (int ch = 0; ch < 4; ++ch) {
        const int hw = ch * 1024 + t * 4;
        float4 fi = *(const float4*)&idxf[hw];
        int k0 = (int)fi.x, k1 = (int)fi.y, k2 = (int)fi.z, k3 = (int)fi.w;
#pragma unroll
        for (int dl = 0; dl < 8; ++dl) {
            size_t off = zb + (size_t)(dg * 8 + dl) * HW + hw;
            float4 zv = *(const float4*)&z[off];
            float4 e;
            e.x = et[dl * 1024 + k0];
            e.y = et[dl * 1024 + k1];
            e.z = et[dl * 1024 + k2];
            e.w = et[dl * 1024 + k3];
            *(float4*)&out[off] = e;
            float df;
            df = e.x - zv.x; lacc = fmaf(df, df, lacc);
            df = e.y - zv.y; lacc = fmaf(df, df, lacc);
            df = e.z - zv.z; lacc = fmaf(df, df, lacc);
            df = e.w - zv.w; lacc = fmaf(df, df, lacc);
        }
    }
#pragma unroll
    for (int off = 32; off > 0; off >>= 1) lacc += __shfl_down(lacc, off, 64);
    if (lane == 0) wsum[w] = lacc;
    __syncthreads();
    if (t == 0) {
        double tot = (double)wsum[0] + (double)wsum[1] + (double)wsum[2] + (double)wsum[3];
        atomicAdd(lsum, tot);
    }
}

__global__ void vq_final(const double* __restrict__ lsum, float* __restrict__ out)
{
    out[OUT_LOSS] = (float)(0.25 * (lsum[0] / (double)OUT_Z));
}

extern "C" void kernel_launch(void* const* d_in, const int* in_sizes, int n_in,
                              void* d_out, int out_size, void* d_ws, size_t ws_size,
                              hipStream_t stream)
{
    const float* z = (const float*)d_in[0];
    const float* emb = (const float*)d_in[1];
    float* out = (float*)d_out;
    char* w = (char*)d_ws;

    float* esq = (float*)(w + WS_ESQ);
    _Float16* eh = (_Float16*)(w + WS_EH);
    uint2* eh2 = (uint2*)(w + WS_EH);
    int* hlist = (int*)(w + WS_HLIST);
    int* hcnt = (int*)(w + WS_HCNT);
    double* lsum = (double*)(w + WS_LSUM);
    float* embT = (float*)(w + WS_EMBT);
    uint4* ehP = (uint4*)(w + WS_EHP);

    int use_embT = (ws_size >= (size_t)WS_EMBT + (size_t)DD * KK * sizeof(float)) ? 1 : 0;
    int use_ehp = (ws_size >= (size_t)WS_EHP + (size_t)KK * DD * sizeof(_Float16)) ? 1 : 0;

    vq_prep<<<dim3(52), dim3(256), 0, stream>>>(emb, esq, eh2, hcnt, lsum, embT, use_embT,
                                                ehP, use_ehp);
    vq_zt<<<dim3(1024), dim3(256), 0, stream>>>(z, out);
    vq_score<<<dim3(1024), dim3(256), 0, stream>>>(out, eh, ehP, esq, hlist, hcnt, use_ehp);
    vq_hard<<<dim3(1024), dim3(256), 0, stream>>>(z, emb, embT, esq, hlist, hcnt, out,
                                                  use_embT);
    vq_out<<<dim3(512), dim3(256), 0, stream>>>(z, emb, embT, out, lsum, use_embT);
    vq_final<<<dim3(1), dim3(1), 0, stream>>>(lsum, out);
}

// Round 4
// 245.039 us; speedup vs baseline: 1.1356x; 1.1095x over previous
//
#include <hip/hip_runtime.h>

#define DD 256
#define KK 1024
#define HW 4096
#define NROWSZ 65536
#define OUT_Z 16777216
#define OUT_IDX OUT_Z
#define OUT_LOSS (OUT_Z + NROWSZ)

#define MARGIN 4.5e-4f

// ws layout (bytes)
#define WS_ESQ   0          // float[1024]
#define WS_EH    4096       // _Float16[262144] emb fp16 [k][d] (fallback B path)
#define WS_HLIST 528384     // int[65536]
#define WS_HCNT  790528     // int
#define WS_LSUM  790536     // double
#define WS_EMBT  791552     // float[256*1024] = 1 MB, emb^T [d][k]
#define WS_EHP   1840128    // _Float16 fragment-ordered emb: 512 KB

typedef _Float16 f16x8 __attribute__((ext_vector_type(8)));
typedef float f32x4 __attribute__((ext_vector_type(4)));
union U16x8 { uint4 u; f16x8 h; };
typedef unsigned long long u64;

static __device__ __forceinline__ u64 umin64(u64 a, u64 b) { return a < b ? a : b; }
static __device__ __forceinline__ unsigned pk16(float a, float b) {
    _Float16 ha = (_Float16)a, hb = (_Float16)b;
    return (unsigned)__builtin_bit_cast(unsigned short, ha)
         | ((unsigned)__builtin_bit_cast(unsigned short, hb) << 16);
}

// ---------------- prep: esq exact, eh fp16, embT fp32, ehP fragment-order ----------
__global__ void vq_prep(const float* __restrict__ emb, float* __restrict__ esq,
                        uint2* __restrict__ eh2, int* __restrict__ hcnt,
                        double* __restrict__ lsum, float* __restrict__ embT,
                        int use_embT, uint4* __restrict__ ehP, int use_ehp)
{
    const int bid = blockIdx.x;
    const int t = threadIdx.x;
    if (bid == 0 && t == 0) { *hcnt = 0; *lsum = 0.0; }

    if (bid < 4) {
        // esq: numpy pairwise-8 exact
        int k = bid * 256 + t;
        const float* e = emb + (size_t)k * DD;
        float blk[2];
#pragma unroll
        for (int b2 = 0; b2 < 2; ++b2) {
            const float* p = e + b2 * 128;
            float r[8];
#pragma unroll
            for (int j = 0; j < 8; ++j) r[j] = __fmul_rn(p[j], p[j]);
            for (int i = 8; i < 128; i += 8) {
#pragma unroll
                for (int j = 0; j < 8; ++j)
                    r[j] = __fadd_rn(r[j], __fmul_rn(p[i + j], p[i + j]));
            }
            blk[b2] = __fadd_rn(__fadd_rn(__fadd_rn(r[0], r[1]), __fadd_rn(r[2], r[3])),
                                __fadd_rn(__fadd_rn(r[4], r[5]), __fadd_rn(r[6], r[7])));
        }
        esq[k] = __fadd_rn(blk[0], blk[1]);
    } else if (bid < 20) {
        // eh fp16 [k][d] (fallback)
        int tid = (bid - 4) * 256 + t;
        const float4* e4 = (const float4*)emb;
#pragma unroll
        for (int i = 0; i < 16; ++i) {
            int idx = i * 4096 + tid;
            float4 v = e4[idx];
            eh2[idx] = make_uint2(pk16(v.x, v.y), pk16(v.z, v.w));
        }
    } else if (bid < 36) {
        // embT [d][k] fp32
        if (!use_embT) return;
        int u = bid - 20;
        int k = u * 64 + (t >> 2);
        int c = t & 3;
        const float4* e4 = (const float4*)(emb + (size_t)k * DD);
#pragma unroll
        for (int i = 0; i < 16; ++i) {
            float4 v = e4[c * 16 + i];
            int d = c * 64 + i * 4;
            embT[(size_t)(d + 0) * KK + k] = v.x;
            embT[(size_t)(d + 1) * KK + k] = v.y;
            embT[(size_t)(d + 2) * KK + k] = v.z;
            embT[(size_t)(d + 3) * KK + k] = v.w;
        }
    } else {
        // ehP: fragment-ordered fp16 B. uint4 index L = ((tt*2+wc)*8+ds)*64 + lane
        // holds eh[tt*32 + wc*16 + (lane&15)][ds*32 + (lane>>4)*8 .. +8]
        if (!use_ehp) return;
#pragma unroll
        for (int it = 0; it < 8; ++it) {
            int L = ((bid - 36) * 8 + it) * 256 + t;
            int lane = L & 63, ds = (L >> 6) & 7, wcq = (L >> 9) & 1, tt = L >> 10;
            int col = lane & 15, quad = lane >> 4;
            int code = tt * 32 + wcq * 16 + col;
            int d0 = ds * 32 + quad * 8;
            const float* e = emb + (size_t)code * DD + d0;
            float4 a = *(const float4*)e;
            float4 c4 = *(const float4*)(e + 4);
            ehP[L] = make_uint4(pk16(a.x, a.y), pk16(a.z, a.w),
                                pk16(c4.x, c4.y), pk16(c4.z, c4.w));
        }
    }
}

// ---------------- score: 256-row tile, A in LDS->regs, B streamed from L2 ----------
// 512 threads = 8 waves = 4 row-groups (64 rows) x 2 code-halves.
// LDS: zh 128 KB (fp16 [256 rows][256 d], XOR-swizzled) + esq 4 KB + cand 4 KB.
// Main loop barrier-free: B-fragments loaded straight from ehP (L2/L1-resident).
__launch_bounds__(512, 2)
__global__ void vq_score(const float* __restrict__ z, const _Float16* __restrict__ eh,
                         const uint4* __restrict__ ehP, const float* __restrict__ esq,
                         float* __restrict__ out, int* __restrict__ hlist,
                         int* __restrict__ hcnt, int use_ehp)
{
    __shared__ __align__(16) char zh[256 * 512];   // 128 KB
    __shared__ float esq_s[1024];
    __shared__ uint2 cand[256][2];

    const int t = threadIdx.x;
    const int lane = t & 63;
    const int w = t >> 6;           // 8 waves
    const int col = lane & 15;
    const int quad = lane >> 4;
    const int wr = w >> 1;          // row group: rows [wr*64, wr*64+64)
    const int wc = w & 1;           // code half of each 32-code tile

    const int n0 = blockIdx.x * 256;
    const int b = n0 >> 12;
    const int hw0 = n0 & (HW - 1);

    // ---- stage z -> zh fp16 (coalesced 1KB global reads; swizzled LDS writes)
    {
        const float* zb2 = z + (size_t)b * DD * HW + hw0;
#pragma unroll 4
        for (int i = 0; i < 32; ++i) {
            const int d = w * 32 + i;
            float4 v = *(const float4*)(zb2 + (size_t)d * HW + lane * 4);
            float va[4] = {v.x, v.y, v.z, v.w};
#pragma unroll
            for (int c = 0; c < 4; ++c) {
                const int row = lane * 4 + c;
                *(_Float16*)(zh + (size_t)row * 512 + ((d * 2) ^ ((row & 7) << 4)))
                    = (_Float16)va[c];
            }
        }
        esq_s[t] = esq[t];
        esq_s[512 + t] = esq[512 + t];
    }
    __syncthreads();

    // ---- A-fragments for this wave's 64 rows (128 VGPRs)
    U16x8 af[4][8];
#pragma unroll
    for (int nt = 0; nt < 4; ++nt) {
        const int row = wr * 64 + nt * 16 + col;
        const int sw = (row & 7) << 4;
#pragma unroll
        for (int ds = 0; ds < 8; ++ds)
            af[nt][ds].u = *(const uint4*)(zh + (size_t)row * 512
                                           + ((ds * 64 + quad * 16) ^ sw));
    }

    unsigned t1[16], t2[16];
#pragma unroll
    for (int i = 0; i < 16; ++i) { t1[i] = 0xFFFFFFFFu; t2[i] = 0xFFFFFFFFu; }

    if (use_ehp) {
        const uint4* bp = ehP + (size_t)wc * 512 + lane;   // [tt][wc][ds][lane]
#pragma unroll 2
        for (int tt = 0; tt < 32; ++tt) {
            const uint4* p = bp + (size_t)tt * 1024;
            U16x8 bf[8];
#pragma unroll
            for (int ds = 0; ds < 8; ++ds) bf[ds].u = p[ds * 64];
            const int code = tt * 32 + wc * 16 + col;
            const float eq1 = 1.0f + esq_s[code];
            f32x4 acc[4];
#pragma unroll
            for (int nt = 0; nt < 4; ++nt) acc[nt] = (f32x4)0.0f;
#pragma unroll
            for (int ds = 0; ds < 8; ++ds)
#pragma unroll
                for (int nt = 0; nt < 4; ++nt)
                    acc[nt] = __builtin_amdgcn_mfma_f32_16x16x32_f16(af[nt][ds].h, bf[ds].h,
                                                                     acc[nt], 0, 0, 0);
#pragma unroll
            for (int nt = 0; nt < 4; ++nt)
#pragma unroll
                for (int r = 0; r < 4; ++r) {
                    float s = fmaf(-2.0f, acc[nt][r], eq1);
                    unsigned k = (__float_as_uint(s) & 0xFFFFFC00u) | (unsigned)code;
                    int mi = nt * 4 + r;
                    t2[mi] = min(t2[mi], max(t1[mi], k));
                    t1[mi] = min(t1[mi], k);
                }
        }
    } else {
        const uint4* ehq = (const uint4*)eh;
        for (int tt = 0; tt < 32; ++tt) {
            const int code = tt * 32 + wc * 16 + col;
            const uint4* bp = ehq + (size_t)code * 32 + quad;
            U16x8 bf[8];
#pragma unroll
            for (int ds = 0; ds < 8; ++ds) bf[ds].u = bp[ds * 4];
            const float eq1 = 1.0f + esq_s[code];
            f32x4 acc[4];
#pragma unroll
            for (int nt = 0; nt < 4; ++nt) acc[nt] = (f32x4)0.0f;
#pragma unroll
            for (int ds = 0; ds < 8; ++ds)
#pragma unroll
                for (int nt = 0; nt < 4; ++nt)
                    acc[nt] = __builtin_amdgcn_mfma_f32_16x16x32_f16(af[nt][ds].h, bf[ds].h,
                                                                     acc[nt], 0, 0, 0);
#pragma unroll
            for (int nt = 0; nt < 4; ++nt)
#pragma unroll
                for (int r = 0; r < 4; ++r) {
                    float s = fmaf(-2.0f, acc[nt][r], eq1);
                    unsigned k = (__float_as_uint(s) & 0xFFFFFC00u) | (unsigned)code;
                    int mi = nt * 4 + r;
                    t2[mi] = min(t2[mi], max(t1[mi], k));
                    t1[mi] = min(t1[mi], k);
                }
        }
    }

    // ---- cross-col (16-lane) top2 merge; exclusive (row, wc) ownership
#pragma unroll
    for (int mi = 0; mi < 16; ++mi) {
        unsigned a = t1[mi], bb = t2[mi];
#pragma unroll
        for (int off = 1; off < 16; off <<= 1) {
            unsigned o1 = __shfl_xor(a, off, 16);
            unsigned o2 = __shfl_xor(bb, off, 16);
            unsigned mx = max(a, o1);
            a = min(a, o1);
            bb = min(min(bb, o2), mx);
        }
        if (col == 0)
            cand[wr * 64 + (mi >> 2) * 16 + quad * 4 + (mi & 3)][wc] = make_uint2(a, bb);
    }
    __syncthreads();

    // ---- merge 2 code-halves + margin routing (idx only; hard rows -> hlist)
    if (t < 256) {
        uint2 c0 = cand[t][0], c1 = cand[t][1];
        unsigned mx = max(c0.x, c1.x);
        unsigned a = min(c0.x, c1.x);
        unsigned bb = min(min(c0.y, c1.y), mx);
        float s1 = __uint_as_float(a & 0xFFFFFC00u);
        float s2 = __uint_as_float(bb & 0xFFFFFC00u);
        int k1 = (int)(a & 1023u);
        if (__fsub_rn(s2, s1) > MARGIN) {
            out[OUT_IDX + n0 + t] = (float)k1;
        } else {
            int pos = atomicAdd(hcnt, 1);
            hlist[pos] = n0 + t;
        }
    }
}

// ---- hard-path dot products (bit-exact sequential-d fma chain) --------------------
template<int USET>
static __device__ __forceinline__ void dot_codes(const float4* __restrict__ embT4,
                                                 const float4* __restrict__ emb4,
                                                 const float4* __restrict__ zb4,
                                                 int t, float (&acc_)[8][4])
{
#pragma unroll 2
    for (int dc = 0; dc < 64; ++dc) {
        float4 e0, e1, e2, e3;
        if (USET) {
            e0 = embT4[(size_t)(dc * 4 + 0) * 256 + t];
            e1 = embT4[(size_t)(dc * 4 + 1) * 256 + t];
            e2 = embT4[(size_t)(dc * 4 + 2) * 256 + t];
            e3 = embT4[(size_t)(dc * 4 + 3) * 256 + t];
        } else {
            float4 a0 = emb4[(size_t)(4 * t + 0) * 64 + dc];
            float4 a1 = emb4[(size_t)(4 * t + 1) * 64 + dc];
            float4 a2 = emb4[(size_t)(4 * t + 2) * 64 + dc];
            float4 a3 = emb4[(size_t)(4 * t + 3) * 64 + dc];
            e0 = make_float4(a0.x, a1.x, a2.x, a3.x);
            e1 = make_float4(a0.y, a1.y, a2.y, a3.y);
            e2 = make_float4(a0.z, a1.z, a2.z, a3.z);
            e3 = make_float4(a0.w, a1.w, a2.w, a3.w);
        }
#pragma unroll
        for (int j = 0; j < 8; ++j) {
            float4 zv = zb4[j * 64 + dc];
            acc_[j][0] = fmaf(zv.x, e0.x, acc_[j][0]);
            acc_[j][1] = fmaf(zv.x, e0.y, acc_[j][1]);
            acc_[j][2] = fmaf(zv.x, e0.z, acc_[j][2]);
            acc_[j][3] = fmaf(zv.x, e0.w, acc_[j][3]);
            acc_[j][0] = fmaf(zv.y, e1.x, acc_[j][0]);
            acc_[j][1] = fmaf(zv.y, e1.y, acc_[j][1]);
            acc_[j][2] = fmaf(zv.y, e1.z, acc_[j][2]);
            acc_[j][3] = fmaf(zv.y, e1.w, acc_[j][3]);
            acc_[j][0] = fmaf(zv.z, e2.x, acc_[j][0]);
            acc_[j][1] = fmaf(zv.z, e2.y, acc_[j][1]);
            acc_[j][2] = fmaf(zv.z, e2.z, acc_[j][2]);
            acc_[j][3] = fmaf(zv.z, e2.w, acc_[j][3]);
            acc_[j][0] = fmaf(zv.w, e3.x, acc_[j][0]);
            acc_[j][1] = fmaf(zv.w, e3.y, acc_[j][1]);
            acc_[j][2] = fmaf(zv.w, e3.z, acc_[j][2]);
            acc_[j][3] = fmaf(zv.w, e3.w, acc_[j][3]);
        }
    }
}

// ---------------- hard: exact fp32 rescan -> idx only ------------------------------
__launch_bounds__(256)
__global__ void vq_hard(const float* __restrict__ z, const float* __restrict__ emb,
                        const float* __restrict__ embT, const float* __restrict__ esq,
                        const int* __restrict__ hlist, const int* __restrict__ hcnt,
                        float* __restrict__ out, int use_embT)
{
    __shared__ __align__(16) float zbuf[8 * 256];
    __shared__ float chains[8][16];
    __shared__ float zq_s[8];
    __shared__ int rows_s[8];
    __shared__ u64 red[4][8];

    const int t = threadIdx.x;
    const int lane = t & 63;
    const int w = t >> 6;
    const int count = *hcnt;

    const float4* embT4 = (const float4*)embT;
    const float4* emb4 = (const float4*)emb;
    const float4* zb4 = (const float4*)zbuf;
    const float4 eqv4 = ((const float4*)esq)[t];
    const float eqa[4] = {eqv4.x, eqv4.y, eqv4.z, eqv4.w};

    for (int g = blockIdx.x; g * 8 < count; g += gridDim.x) {
        __syncthreads();
        if (t < 8) {
            int p = g * 8 + t;
            rows_s[t] = (p < count) ? hlist[p] : -1;
        }
        __syncthreads();

        {
            const int j = t >> 5, dpos = t & 31;
            const int r = rows_s[j];
            float4 v0 = make_float4(0.f, 0.f, 0.f, 0.f), v1 = v0;
            if (r >= 0) {
                const float* zp = z + (size_t)(r >> 12) * (DD * HW) + (r & (HW - 1));
                const int d0 = dpos * 8;
                v0.x = zp[(size_t)(d0 + 0) * HW];
                v0.y = zp[(size_t)(d0 + 1) * HW];
                v0.z = zp[(size_t)(d0 + 2) * HW];
                v0.w = zp[(size_t)(d0 + 3) * HW];
                v1.x = zp[(size_t)(d0 + 4) * HW];
                v1.y = zp[(size_t)(d0 + 5) * HW];
                v1.z = zp[(size_t)(d0 + 6) * HW];
                v1.w = zp[(size_t)(d0 + 7) * HW];
            }
            *(float4*)&zbuf[j * 256 + dpos * 8] = v0;
            *(float4*)&zbuf[j * 256 + dpos * 8 + 4] = v1;
        }
        __syncthreads();

        if (t < 128) {
            int j = t >> 4, c = t & 15, b2 = c >> 3, jj = c & 7;
            const float* p = &zbuf[j * 256];
            int base = b2 * 128 + jj;
            float v = p[base];
            float acc = __fmul_rn(v, v);
            for (int i = 1; i < 16; ++i) {
                float u = p[base + i * 8];
                acc = __fadd_rn(acc, __fmul_rn(u, u));
            }
            chains[j][c] = acc;
        }
        __syncthreads();
        if (t < 8) {
            const float* c = chains[t];
            float b0 = __fadd_rn(__fadd_rn(__fadd_rn(c[0], c[1]), __fadd_rn(c[2], c[3])),
                                 __fadd_rn(__fadd_rn(c[4], c[5]), __fadd_rn(c[6], c[7])));
            float b1 = __fadd_rn(__fadd_rn(__fadd_rn(c[8], c[9]), __fadd_rn(c[10], c[11])),
                                 __fadd_rn(__fadd_rn(c[12], c[13]), __fadd_rn(c[14], c[15])));
            zq_s[t] = __fadd_rn(b0, b1);
        }
        __syncthreads();

        float acc_[8][4];
#pragma unroll
        for (int j = 0; j < 8; ++j)
#pragma unroll
            for (int kk = 0; kk < 4; ++kk) acc_[j][kk] = 0.0f;

        if (use_embT) dot_codes<1>(embT4, emb4, zb4, t, acc_);
        else          dot_codes<0>(embT4, emb4, zb4, t, acc_);

#pragma unroll
        for (int j = 0; j < 8; ++j) {
            u64 m = ~0ull;
#pragma unroll
            for (int kk = 0; kk < 4; ++kk) {
                float s = __fsub_rn(__fadd_rn(zq_s[j], eqa[kk]),
                                    __fmul_rn(2.0f, acc_[j][kk]));
                u64 p = ((u64)__float_as_uint(s) << 32) | (unsigned)(4 * t + kk);
                m = umin64(m, p);
            }
#pragma unroll
            for (int off = 1; off < 64; off <<= 1)
                m = umin64(m, __shfl_xor(m, off, 64));
            if (lane == 0) red[w][j] = m;
        }
        __syncthreads();
        if (t < 8) {
            u64 m = umin64(umin64(red[0][t], red[1][t]), umin64(red[2][t], red[3][t]));
            int r = rows_s[t];
            if (r >= 0) out[OUT_IDX + r] = (float)(int)(m & 0xffffffffu);
        }
    }
}

// ---------------- out: d-major contiguous scatter + loss for ALL rows --------------
__launch_bounds__(256)
__global__ void vq_out(const float* __restrict__ z, const float* __restrict__ emb,
                       const float* __restrict__ embT, float* out,
                       double* __restrict__ lsum, int use_embT)
{
    __shared__ float et[8 * 1024];   // embT rows [dg*8 .. +8)
    __shared__ float wsum[4];

    const int t = threadIdx.x;
    const int lane = t & 63;
    const int w = t >> 6;
    const int bb = blockIdx.x >> 5;     // batch
    const int dg = blockIdx.x & 31;     // d-group (8 d)

    if (use_embT) {
#pragma unroll
        for (int c = 0; c < 8; ++c)
            *(float4*)&et[c * 1024 + t * 4] =
                *(const float4*)&embT[(size_t)(dg * 8 + c) * KK + t * 4];
    } else {
        for (int i = 0; i < 32; ++i) {
            int kk = i * 256 + t;
            et[kk] = emb[(size_t)(kk & 1023) * DD + dg * 8 + (kk >> 10)];
        }
    }
    __syncthreads();

    float lacc = 0.f;
    const size_t zb = (size_t)bb * DD * HW;
    const float* idxf = out + OUT_IDX + (size_t)bb * HW;
#pragma unroll
    for (int ch = 0; ch < 4; ++ch) {
        const int hw = ch * 1024 + t * 4;
        float4 fi = *(const float4*)&idxf[hw];
        int k0 = (int)fi.x, k1 = (int)fi.y, k2 = (int)fi.z, k3 = (int)fi.w;
#pragma unroll
        for (int dl = 0; dl < 8; ++dl) {
            size_t off = zb + (size_t)(dg * 8 + dl) * HW + hw;
            float4 zv = *(const float4*)&z[off];
            float4 e;
            e.x = et[dl * 1024 + k0];
            e.y = et[dl * 1024 + k1];
            e.z = et[dl * 1024 + k2];
            e.w = et[dl * 1024 + k3];
            *(float4*)&out[off] = e;
            float df;
            df = e.x - zv.x; lacc = fmaf(df, df, lacc);
            df = e.y - zv.y; lacc = fmaf(df, df, lacc);
            df = e.z - zv.z; lacc = fmaf(df, df, lacc);
            df = e.w - zv.w; lacc = fmaf(df, df, lacc);
        }
    }
#pragma unroll
    for (int off = 32; off > 0; off >>= 1) lacc += __shfl_down(lacc, off, 64);
    if (lane == 0) wsum[w] = lacc;
    __syncthreads();
    if (t == 0) {
        double tot = (double)wsum[0] + (double)wsum[1] + (double)wsum[2] + (double)wsum[3];
        atomicAdd(lsum, tot);
    }
}

__global__ void vq_final(const double* __restrict__ lsum, float* __restrict__ out)
{
    out[OUT_LOSS] = (float)(0.25 * (lsum[0] / (double)OUT_Z));
}

extern "C" void kernel_launch(void* const* d_in, const int* in_sizes, int n_in,
                              void* d_out, int out_size, void* d_ws, size_t ws_size,
                              hipStream_t stream)
{
    const float* z = (const float*)d_in[0];
    const float* emb = (const float*)d_in[1];
    float* out = (float*)d_out;
    char* w = (char*)d_ws;

    float* esq = (float*)(w + WS_ESQ);
    _Float16* eh = (_Float16*)(w + WS_EH);
    uint2* eh2 = (uint2*)(w + WS_EH);
    int* hlist = (int*)(w + WS_HLIST);
    int* hcnt = (int*)(w + WS_HCNT);
    double* lsum = (double*)(w + WS_LSUM);
    float* embT = (float*)(w + WS_EMBT);
    uint4* ehP = (uint4*)(w + WS_EHP);

    int use_embT = (ws_size >= (size_t)WS_EMBT + (size_t)DD * KK * sizeof(float)) ? 1 : 0;
    int use_ehp = (ws_size >= (size_t)WS_EHP + (size_t)KK * DD * sizeof(_Float16)) ? 1 : 0;

    vq_prep<<<dim3(52), dim3(256), 0, stream>>>(emb, esq, eh2, hcnt, lsum, embT, use_embT,
                                                ehP, use_ehp);
    vq_score<<<dim3(256), dim3(512), 0, stream>>>(z, eh, ehP, esq, out, hlist, hcnt,
                                                  use_ehp);
    vq_hard<<<dim3(1024), dim3(256), 0, stream>>>(z, emb, embT, esq, hlist, hcnt, out,
                                                  use_embT);
    vq_out<<<dim3(512), dim3(256), 0, stream>>>(z, emb, embT, out, lsum, use_embT);
    vq_final<<<dim3(1), dim3(1), 0, stream>>>(lsum, out);
}